// Round 1
// baseline (1597.018 us; speedup 1.0000x reference)
//
#include <hip/hip_runtime.h>
#include <hip/hip_fp16.h>

#define NA 100000
#define NB 200000
#define MAXNB 6
#define AF 133
#define BF 147
#define H 300
#define HP 320     // padded row width for fp16 intermediates (640B rows, 16B aligned)
#define NP 384     // GEMM N padding (3 x BN=128)
#define KP_I 160
#define KP_H 320
#define KP_O 448

typedef _Float16 f16;
typedef __attribute__((ext_vector_type(8))) _Float16 f16x8;
typedef __attribute__((ext_vector_type(4))) float f32x4;

// ---- pad + transpose weights to [n][k] fp16 -------------------------------
__global__ void prep_w(const float* __restrict__ src, f16* __restrict__ dst,
                       int Ksrc, int Nsrc, int KP) {
  int idx = blockIdx.x * blockDim.x + threadIdx.x;
  if (idx >= NP * KP) return;
  int n = idx / KP, k = idx - n * KP;
  float v = (n < Nsrc && k < Ksrc) ? src[k * Nsrc + n] : 0.0f;
  dst[idx] = (f16)v;
}

// ---- a_msg[a][:] = sum_t msg[a2b[a][t]][:] --------------------------------
__global__ void gather_sum_kernel(const f16* __restrict__ msg,
                                  const int* __restrict__ a2b,
                                  f16* __restrict__ amsg) {
  int idx = blockIdx.x * blockDim.x + threadIdx.x;
  if (idx >= NA * 40) return;
  int a = idx / 40;
  int c = (idx - a * 40) * 8;
  const int* nbr = &a2b[a * MAXNB];
  float acc[8] = {0.f,0.f,0.f,0.f,0.f,0.f,0.f,0.f};
#pragma unroll
  for (int t = 0; t < MAXNB; ++t) {
    int r = nbr[t];
    f16x8 v = *(const f16x8*)&msg[(size_t)r * HP + c];
#pragma unroll
    for (int j = 0; j < 8; ++j) acc[j] += (float)v[j];
  }
  f16x8 o;
#pragma unroll
  for (int j = 0; j < 8; ++j) o[j] = (f16)acc[j];
  *(f16x8*)&amsg[(size_t)a * HP + c] = o;
}

// ---- unified GEMM: 128x128 tile, 4 waves (2x2), BK=32, 16x16x32 f16 MFMA --
// MODE 0: inp = f_bonds @ W_i            (writes inp fp16 + msg = relu(inp))
// MODE 1: msg' = relu(inp + (a_msg[b2a] - msg[b2revb]) @ W_h)
// MODE 2: out = relu([f_atoms, a_msg] @ W_o + b_o)   (fp32 to d_out)
template <int MODE>
__global__ __launch_bounds__(256)
void gemm_kernel(const float* __restrict__ fbonds,
                 const float* __restrict__ fatoms,
                 const f16* __restrict__ amsg,
                 const f16* __restrict__ msg_in,
                 const int* __restrict__ b2a,
                 const int* __restrict__ b2revb,
                 const f16* __restrict__ Wp,
                 const f16* __restrict__ inp_r,
                 const float* __restrict__ b_o,
                 f16* __restrict__ out_inp,
                 f16* __restrict__ out_msg,
                 float* __restrict__ out_f32) {
  constexpr int KP = (MODE == 0) ? KP_I : (MODE == 1) ? KP_H : KP_O;
  constexpr int KSTEPS = KP / 32;
  constexpr int M = (MODE == 2) ? NA : NB;

  __shared__ f16 As[128][40];
  __shared__ f16 Bs[128][40];

  const int mb = blockIdx.x, nb = blockIdx.y;
  const int tid = threadIdx.x;
  const int lane = tid & 63, wid = tid >> 6;
  const int wr = wid >> 1, wc = wid & 1;

  f32x4 acc[4][4] = {};

  const int arow = tid >> 1;       // 0..127 (used for both A and B staging)
  const int k0 = (tid & 1) * 16;   // 0 or 16
  const int m_g = mb * 128 + arow;
  const int n_g = nb * 128 + arow;

  int ra = 0, rb = 0;
  if (MODE == 1 && m_g < NB) { ra = b2a[m_g]; rb = b2revb[m_g]; }

  for (int ks = 0; ks < KSTEPS; ++ks) {
    const int kbase = ks * 32 + k0;

    // build 16 halves of the A tile row
    f16 tmp[16];
    if (MODE == 0) {
#pragma unroll
      for (int j = 0; j < 16; ++j) {
        int kk = kbase + j;
        float v = (m_g < NB && kk < BF) ? fbonds[(size_t)m_g * BF + kk] : 0.0f;
        tmp[j] = (f16)v;
      }
    } else if (MODE == 1) {
      if (m_g < NB) {
        f16x8 va0 = *(const f16x8*)&amsg[(size_t)ra * HP + kbase];
        f16x8 va1 = *(const f16x8*)&amsg[(size_t)ra * HP + kbase + 8];
        f16x8 vb0 = *(const f16x8*)&msg_in[(size_t)rb * HP + kbase];
        f16x8 vb1 = *(const f16x8*)&msg_in[(size_t)rb * HP + kbase + 8];
        f16x8 d0 = va0 - vb0, d1 = va1 - vb1;
#pragma unroll
        for (int j = 0; j < 8; ++j) { tmp[j] = d0[j]; tmp[8 + j] = d1[j]; }
      } else {
#pragma unroll
        for (int j = 0; j < 16; ++j) tmp[j] = (f16)0.0f;
      }
    } else {
#pragma unroll
      for (int j = 0; j < 16; ++j) {
        int kk = kbase + j;
        f16 v = (f16)0.0f;
        if (m_g < NA) {
          if (kk < AF) v = (f16)fatoms[(size_t)m_g * AF + kk];
          else if (kk < AF + H) v = amsg[(size_t)m_g * HP + (kk - AF)];
        }
        tmp[j] = v;
      }
    }

    // B tile (weights pre-transposed [n][k], always in range)
    f16x8 wb0 = *(const f16x8*)&Wp[(size_t)n_g * KP + kbase];
    f16x8 wb1 = *(const f16x8*)&Wp[(size_t)n_g * KP + kbase + 8];

    __syncthreads();  // previous iteration's LDS reads done
    *(f16x8*)&As[arow][k0] = *(f16x8*)&tmp[0];
    *(f16x8*)&As[arow][k0 + 8] = *(f16x8*)&tmp[8];
    *(f16x8*)&Bs[arow][k0] = wb0;
    *(f16x8*)&Bs[arow][k0 + 8] = wb1;
    __syncthreads();

    const int row16 = lane & 15, kh = (lane >> 4) * 8;
    f16x8 af[4], bfr[4];
#pragma unroll
    for (int m = 0; m < 4; ++m)
      af[m] = *(const f16x8*)&As[wr * 64 + m * 16 + row16][kh];
#pragma unroll
    for (int n = 0; n < 4; ++n)
      bfr[n] = *(const f16x8*)&Bs[wc * 64 + n * 16 + row16][kh];
#pragma unroll
    for (int m = 0; m < 4; ++m)
#pragma unroll
      for (int n = 0; n < 4; ++n)
        acc[m][n] = __builtin_amdgcn_mfma_f32_16x16x32_f16(af[m], bfr[n], acc[m][n], 0, 0, 0);
  }

  // epilogue: C/D layout col = lane&15, row = (lane>>4)*4 + j  [m89]
  const int row16 = lane & 15;
  const int rquad = (lane >> 4) * 4;
#pragma unroll
  for (int m = 0; m < 4; ++m) {
#pragma unroll
    for (int n = 0; n < 4; ++n) {
      int col = nb * 128 + wc * 64 + n * 16 + row16;
#pragma unroll
      for (int j = 0; j < 4; ++j) {
        int row = mb * 128 + wr * 64 + m * 16 + rquad + j;
        float v = acc[m][n][j];
        if (MODE == 0) {
          if (row < NB && col < HP) {
            size_t o = (size_t)row * HP + col;
            out_inp[o] = (f16)v;
            out_msg[o] = (f16)fmaxf(v, 0.0f);
          }
        } else if (MODE == 1) {
          if (row < NB && col < HP) {
            size_t o = (size_t)row * HP + col;
            float x = v + (float)inp_r[o];
            out_msg[o] = (f16)fmaxf(x, 0.0f);
          }
        } else {
          if (row < M && col < H) {
            out_f32[(size_t)row * H + col] = fmaxf(v + b_o[col], 0.0f);
          }
        }
      }
    }
  }
}

extern "C" void kernel_launch(void* const* d_in, const int* in_sizes, int n_in,
                              void* d_out, int out_size, void* d_ws, size_t ws_size,
                              hipStream_t stream) {
  const float* f_atoms = (const float*)d_in[0];
  const float* f_bonds = (const float*)d_in[1];
  const int*   a2b     = (const int*)d_in[2];
  const int*   b2a     = (const int*)d_in[3];
  const int*   b2revb  = (const int*)d_in[4];
  const float* W_i     = (const float*)d_in[5];
  const float* W_h     = (const float*)d_in[6];
  const float* W_o     = (const float*)d_in[7];
  const float* b_o     = (const float*)d_in[8];
  float* out = (float*)d_out;

  char* ws = (char*)d_ws;
  size_t off = 0;
  f16* inp  = (f16*)(ws + off); off += (size_t)NB * HP * 2;
  f16* msgA = (f16*)(ws + off); off += (size_t)NB * HP * 2;
  f16* msgB = (f16*)(ws + off); off += (size_t)NB * HP * 2;
  f16* amsg = (f16*)(ws + off); off += (size_t)NA * HP * 2;
  f16* WiP  = (f16*)(ws + off); off += (size_t)NP * KP_I * 2;
  f16* WhP  = (f16*)(ws + off); off += (size_t)NP * KP_H * 2;
  f16* WoP  = (f16*)(ws + off); off += (size_t)NP * KP_O * 2;
  if (off > ws_size) return;  // insufficient workspace -> visible validation failure

  prep_w<<<(NP * KP_I + 255) / 256, 256, 0, stream>>>(W_i, WiP, BF, H, KP_I);
  prep_w<<<(NP * KP_H + 255) / 256, 256, 0, stream>>>(W_h, WhP, H, H, KP_H);
  prep_w<<<(NP * KP_O + 255) / 256, 256, 0, stream>>>(W_o, WoP, AF + H, H, KP_O);

  dim3 gB((NB + 127) / 128, 3), gA((NA + 127) / 128, 3);
  dim3 gS((NA * 40 + 255) / 256);

  // inp = f_bonds @ W_i ; msgA = relu(inp)
  gemm_kernel<0><<<gB, 256, 0, stream>>>(f_bonds, nullptr, nullptr, nullptr,
                                         nullptr, nullptr, WiP, nullptr, nullptr,
                                         inp, msgA, nullptr);
  // iteration 1
  gather_sum_kernel<<<gS, 256, 0, stream>>>(msgA, a2b, amsg);
  gemm_kernel<1><<<gB, 256, 0, stream>>>(nullptr, nullptr, amsg, msgA,
                                         b2a, b2revb, WhP, inp, nullptr,
                                         nullptr, msgB, nullptr);
  // iteration 2
  gather_sum_kernel<<<gS, 256, 0, stream>>>(msgB, a2b, amsg);
  gemm_kernel<1><<<gB, 256, 0, stream>>>(nullptr, nullptr, amsg, msgB,
                                         b2a, b2revb, WhP, inp, nullptr,
                                         nullptr, msgA, nullptr);
  // readout
  gather_sum_kernel<<<gS, 256, 0, stream>>>(msgA, a2b, amsg);
  gemm_kernel<2><<<gA, 256, 0, stream>>>(nullptr, f_atoms, amsg, nullptr,
                                         nullptr, nullptr, WoP, nullptr, b_o,
                                         nullptr, nullptr, out);
}

// Round 4
// 925.849 us; speedup vs baseline: 1.7249x; 1.7249x over previous
//
#include <hip/hip_runtime.h>
#include <hip/hip_fp16.h>

#define NA 100000
#define NB 200000
#define MAXNB 6
#define AF 133
#define BF 147
#define H 300
#define HP 320     // padded fp16 row width for msg/amsg (640B)
#define AFP 160    // padded fp16 row width for f_bonds/f_atoms
#define NP 384     // GEMM N padding (3 x BN=128)
#define KP_C 480   // uniform K padding: [W_i(160); W_h(320)] and [atoms(160); amsg(320)]

typedef _Float16 f16;
typedef __attribute__((ext_vector_type(8))) _Float16 f16x8;
typedef __attribute__((ext_vector_type(4))) float f32x4;

// ---- fp32 [M][Ks] -> fp16 [M][160] zero-padded ----------------------------
__global__ void conv_pad_f16(const float* __restrict__ src, f16* __restrict__ dst,
                             int M, int Ks) {
  int idx = blockIdx.x * blockDim.x + threadIdx.x;
  if (idx >= M * (AFP / 8)) return;
  int r = idx / (AFP / 8);
  int c = (idx - r * (AFP / 8)) * 8;
  f16x8 o;
#pragma unroll
  for (int j = 0; j < 8; ++j) {
    int k = c + j;
    o[j] = (k < Ks) ? (f16)src[(size_t)r * Ks + k] : (f16)0.0f;
  }
  *(f16x8*)&dst[(size_t)r * AFP + c] = o;
}

// ---- stacked [W_i; W_h] -> [n][k] fp16, k<160: W_i[k][n], k in [160,460): W_h ----
__global__ void prep_w1(const float* __restrict__ Wi, const float* __restrict__ Wh,
                        f16* __restrict__ dst) {
  int idx = blockIdx.x * blockDim.x + threadIdx.x;
  if (idx >= NP * KP_C) return;
  int n = idx / KP_C, k = idx - n * KP_C;
  float v = 0.0f;
  if (n < H) {
    if (k < BF) v = Wi[(size_t)k * H + n];
    else if (k >= AFP && k < AFP + H) v = Wh[(size_t)(k - AFP) * H + n];
  }
  dst[idx] = (f16)v;
}

// ---- W_o remapped for [f_atoms(133->160 pad), amsg(300->320 pad)] ----------
__global__ void prep_wo(const float* __restrict__ src, f16* __restrict__ dst) {
  int idx = blockIdx.x * blockDim.x + threadIdx.x;
  if (idx >= NP * KP_C) return;
  int n = idx / KP_C, k = idx - n * KP_C;
  int ks = -1;
  if (k < AF) ks = k;
  else if (k >= AFP && k < AFP + H) ks = AF + (k - AFP);
  float v = (n < H && ks >= 0) ? src[(size_t)ks * H + n] : 0.0f;
  dst[idx] = (f16)v;
}

// ---- a_msg[a][:] = sum_t msg[a2b[a][t]][:] --------------------------------
__global__ void gather_sum_kernel(const f16* __restrict__ msg,
                                  const int* __restrict__ a2b,
                                  f16* __restrict__ amsg) {
  int idx = blockIdx.x * blockDim.x + threadIdx.x;
  if (idx >= NA * (HP / 8)) return;
  int a = idx / (HP / 8);
  int c = (idx - a * (HP / 8)) * 8;
  const int* nbr = &a2b[(size_t)a * MAXNB];
  float acc[8] = {0.f, 0.f, 0.f, 0.f, 0.f, 0.f, 0.f, 0.f};
#pragma unroll
  for (int t = 0; t < MAXNB; ++t) {
    int r = nbr[t];
    f16x8 v = *(const f16x8*)&msg[(size_t)r * HP + c];
#pragma unroll
    for (int j = 0; j < 8; ++j) acc[j] += (float)v[j];
  }
  f16x8 o;
#pragma unroll
  for (int j = 0; j < 8; ++j) o[j] = (f16)acc[j];
  *(f16x8*)&amsg[(size_t)a * HP + c] = o;
}

// ---- unified GEMM: 128x128 tile, 4 waves (2x2), BK=32, 16x16x32 f16 MFMA --
// MODE 0: msg = relu(fb16 @ W_i)                       (K=160, uses W1P k<160)
// MODE 1: msg' = relu([fb16[m], amsg[b2a]-msg[b2revb]] @ [W_i;W_h])  (K=480)
// MODE 2: out = relu([fa16, amsg] @ W_o + b_o)          (K=480, fp32 out)
template <int MODE>
__global__ __launch_bounds__(256)
void gemm_kernel(const f16* __restrict__ Afp,    // fb16 (MODE 0/1) / fa16 (MODE 2)
                 const f16* __restrict__ amsg,
                 const f16* __restrict__ msg_in,
                 const int* __restrict__ b2a,
                 const int* __restrict__ b2revb,
                 const f16* __restrict__ Wp,     // stride KP_C always
                 const float* __restrict__ b_o,
                 f16* __restrict__ out_msg,
                 float* __restrict__ out_f32) {
  constexpr int KSTEPS = (MODE == 0) ? 5 : 15;
  constexpr int M = (MODE == 2) ? NA : NB;

  __shared__ f16 As[128][40];
  __shared__ f16 Bs[128][40];

  const int mb = blockIdx.x, nb = blockIdx.y;
  const int tid = threadIdx.x;
  const int lane = tid & 63, wid = tid >> 6;
  const int wr = wid >> 1, wc = wid & 1;

  f32x4 acc[4][4] = {};

  const int arow = tid >> 1;       // 0..127 (staging row for both A and B)
  const int k0 = (tid & 1) * 16;   // 0 or 16
  const int m_g = mb * 128 + arow;
  const int n_g = nb * 128 + arow; // < NP always
  const int mrow = (m_g < M) ? m_g : 0;  // clamp: OOB rows masked in epilogue

  int ra = 0, rb = 0;
  if (MODE == 1) { ra = b2a[mrow]; rb = b2revb[mrow]; }

  f16x8 pa0, pa1, pb0, pb1, pw0, pw1;
  const f16x8 zz = {0, 0, 0, 0, 0, 0, 0, 0};

  auto prefetch = [&](int ks) {
    int kbase = ks * 32 + k0;
    if constexpr (MODE == 0) {
      const f16* p = &Afp[(size_t)mrow * AFP + kbase];
      pa0 = *(const f16x8*)p;
      pa1 = *(const f16x8*)(p + 8);
    } else if constexpr (MODE == 1) {
      // AFP=160 is a multiple of 32 -> each k-step lies wholly on one side
      if (kbase < AFP) {
        const f16* p = &Afp[(size_t)mrow * AFP + kbase];
        pa0 = *(const f16x8*)p;
        pa1 = *(const f16x8*)(p + 8);
        pb0 = zz; pb1 = zz;
      } else {
        int kk = kbase - AFP;
        pa0 = *(const f16x8*)&amsg[(size_t)ra * HP + kk];
        pa1 = *(const f16x8*)&amsg[(size_t)ra * HP + kk + 8];
        pb0 = *(const f16x8*)&msg_in[(size_t)rb * HP + kk];
        pb1 = *(const f16x8*)&msg_in[(size_t)rb * HP + kk + 8];
      }
    } else {
      const f16* p = (kbase < AFP) ? &Afp[(size_t)mrow * AFP + kbase]
                                   : &amsg[(size_t)mrow * HP + (kbase - AFP)];
      pa0 = *(const f16x8*)p;
      pa1 = *(const f16x8*)(p + 8);
    }
    const f16* w = &Wp[(size_t)n_g * KP_C + kbase];
    pw0 = *(const f16x8*)w;
    pw1 = *(const f16x8*)(w + 8);
  };

  prefetch(0);

  for (int ks = 0; ks < KSTEPS; ++ks) {
    __syncthreads();  // previous iteration's LDS reads done
    if constexpr (MODE == 1) {
      *(f16x8*)&As[arow][k0]     = pa0 - pb0;
      *(f16x8*)&As[arow][k0 + 8] = pa1 - pb1;
    } else {
      *(f16x8*)&As[arow][k0]     = pa0;
      *(f16x8*)&As[arow][k0 + 8] = pa1;
    }
    *(f16x8*)&Bs[arow][k0]     = pw0;
    *(f16x8*)&Bs[arow][k0 + 8] = pw1;
    __syncthreads();

    // issue next k-step's global loads; latency overlaps ds_read + MFMA phase
    if (ks + 1 < KSTEPS) prefetch(ks + 1);

    const int row16 = lane & 15, kh = (lane >> 4) * 8;
    f16x8 af[4], bfr[4];
#pragma unroll
    for (int m = 0; m < 4; ++m)
      af[m] = *(const f16x8*)&As[wr * 64 + m * 16 + row16][kh];
#pragma unroll
    for (int n = 0; n < 4; ++n)
      bfr[n] = *(const f16x8*)&Bs[wc * 64 + n * 16 + row16][kh];
#pragma unroll
    for (int m = 0; m < 4; ++m)
#pragma unroll
      for (int n = 0; n < 4; ++n)
        acc[m][n] = __builtin_amdgcn_mfma_f32_16x16x32_f16(af[m], bfr[n], acc[m][n], 0, 0, 0);
  }

  // epilogue: C/D layout col = lane&15, row = (lane>>4)*4 + j  [m89]
  const int row16 = lane & 15;
  const int rquad = (lane >> 4) * 4;
#pragma unroll
  for (int m = 0; m < 4; ++m) {
#pragma unroll
    for (int n = 0; n < 4; ++n) {
      int col = nb * 128 + wc * 64 + n * 16 + row16;
#pragma unroll
      for (int j = 0; j < 4; ++j) {
        int row = mb * 128 + wr * 64 + m * 16 + rquad + j;
        float v = acc[m][n][j];
        if (MODE == 2) {
          if (row < M && col < H)
            out_f32[(size_t)row * H + col] = fmaxf(v + b_o[col], 0.0f);
        } else {
          if (row < M && col < HP)
            out_msg[(size_t)row * HP + col] = (f16)fmaxf(v, 0.0f);
        }
      }
    }
  }
}

extern "C" void kernel_launch(void* const* d_in, const int* in_sizes, int n_in,
                              void* d_out, int out_size, void* d_ws, size_t ws_size,
                              hipStream_t stream) {
  const float* f_atoms = (const float*)d_in[0];
  const float* f_bonds = (const float*)d_in[1];
  const int*   a2b     = (const int*)d_in[2];
  const int*   b2a     = (const int*)d_in[3];
  const int*   b2revb  = (const int*)d_in[4];
  const float* W_i     = (const float*)d_in[5];
  const float* W_h     = (const float*)d_in[6];
  const float* W_o     = (const float*)d_in[7];
  const float* b_o     = (const float*)d_in[8];
  float* out = (float*)d_out;

  char* ws = (char*)d_ws;
  size_t off = 0;
  f16* msgA = (f16*)(ws + off); off += (size_t)NB * HP * 2;   // 128.0 MB
  f16* msgB = (f16*)(ws + off); off += (size_t)NB * HP * 2;   // 128.0 MB
  f16* amsg = (f16*)(ws + off); off += (size_t)NA * HP * 2;   //  64.0 MB
  f16* fb16 = (f16*)(ws + off); off += (size_t)NB * AFP * 2;  //  64.0 MB
  f16* fa16 = (f16*)(ws + off); off += (size_t)NA * AFP * 2;  //  32.0 MB
  f16* W1P  = (f16*)(ws + off); off += (size_t)NP * KP_C * 2;
  f16* WoP  = (f16*)(ws + off); off += (size_t)NP * KP_C * 2;
  if (off > ws_size) return;  // total ~416.7 MB

  prep_w1<<<(NP * KP_C + 255) / 256, 256, 0, stream>>>(W_i, W_h, W1P);
  prep_wo<<<(NP * KP_C + 255) / 256, 256, 0, stream>>>(W_o, WoP);
  conv_pad_f16<<<(NB * (AFP / 8) + 255) / 256, 256, 0, stream>>>(f_bonds, fb16, NB, BF);
  conv_pad_f16<<<(NA * (AFP / 8) + 255) / 256, 256, 0, stream>>>(f_atoms, fa16, NA, AF);

  dim3 gB((NB + 127) / 128, 3), gA((NA + 127) / 128, 3);
  dim3 gS((NA * (HP / 8) + 255) / 256);

  // msgA = relu(fb16 @ W_i)
  gemm_kernel<0><<<gB, 256, 0, stream>>>(fb16, nullptr, nullptr,
                                         nullptr, nullptr, W1P, nullptr,
                                         msgA, nullptr);
  // iteration 1: msgB = relu(inp + (amsg[b2a]-msgA[b2revb]) @ W_h)  [fused]
  gather_sum_kernel<<<gS, 256, 0, stream>>>(msgA, a2b, amsg);
  gemm_kernel<1><<<gB, 256, 0, stream>>>(fb16, amsg, msgA,
                                         b2a, b2revb, W1P, nullptr,
                                         msgB, nullptr);
  // iteration 2
  gather_sum_kernel<<<gS, 256, 0, stream>>>(msgB, a2b, amsg);
  gemm_kernel<1><<<gB, 256, 0, stream>>>(fb16, amsg, msgB,
                                         b2a, b2revb, W1P, nullptr,
                                         msgA, nullptr);
  // readout
  gather_sum_kernel<<<gS, 256, 0, stream>>>(msgA, a2b, amsg);
  gemm_kernel<2><<<gA, 256, 0, stream>>>(fa16, amsg, nullptr,
                                         nullptr, nullptr, WoP, b_o,
                                         nullptr, out);
}

// Round 7
// 808.967 us; speedup vs baseline: 1.9741x; 1.1445x over previous
//
#include <hip/hip_runtime.h>
#include <hip/hip_fp16.h>

#define NA 100000
#define NB 200000
#define MAXNB 6
#define AF 133
#define BF 147
#define H 300
#define HP 320     // padded fp16 row width for msg/amsg (640B)
#define AFP 160    // padded fp16 row width for f_bonds/f_atoms
#define NP 320     // weight N padding = BN
#define KP_C 480   // uniform K padding: [W_i(160); W_h(320)] / [atoms(160); amsg(320)]
#define BM 128
#define BN 320
#define BK 32
#define NTH 512

typedef _Float16 f16;
typedef __attribute__((ext_vector_type(8))) _Float16 f16x8;
typedef __attribute__((ext_vector_type(4))) float f32x4;

// ---- fp32 [M][Ks] -> fp16 [M][160] zero-padded ----------------------------
__global__ void conv_pad_f16(const float* __restrict__ src, f16* __restrict__ dst,
                             int M, int Ks) {
  int idx = blockIdx.x * blockDim.x + threadIdx.x;
  if (idx >= M * (AFP / 8)) return;
  int r = idx / (AFP / 8);
  int c = (idx - r * (AFP / 8)) * 8;
  f16x8 o;
#pragma unroll
  for (int j = 0; j < 8; ++j) {
    int k = c + j;
    o[j] = (k < Ks) ? (f16)src[(size_t)r * Ks + k] : (f16)0.0f;
  }
  *(f16x8*)&dst[(size_t)r * AFP + c] = o;
}

// ---- stacked [W_i; W_h] -> [n][k] fp16 ------------------------------------
__global__ void prep_w1(const float* __restrict__ Wi, const float* __restrict__ Wh,
                        f16* __restrict__ dst) {
  int idx = blockIdx.x * blockDim.x + threadIdx.x;
  if (idx >= NP * KP_C) return;
  int n = idx / KP_C, k = idx - n * KP_C;
  float v = 0.0f;
  if (n < H) {
    if (k < BF) v = Wi[(size_t)k * H + n];
    else if (k >= AFP && k < AFP + H) v = Wh[(size_t)(k - AFP) * H + n];
  }
  dst[idx] = (f16)v;
}

// ---- W_o remapped for [f_atoms(133->160 pad), amsg(300->320 pad)] ----------
__global__ void prep_wo(const float* __restrict__ src, f16* __restrict__ dst) {
  int idx = blockIdx.x * blockDim.x + threadIdx.x;
  if (idx >= NP * KP_C) return;
  int n = idx / KP_C, k = idx - n * KP_C;
  int ks = -1;
  if (k < AF) ks = k;
  else if (k >= AFP && k < AFP + H) ks = AF + (k - AFP);
  float v = (n < H && ks >= 0) ? src[(size_t)ks * H + n] : 0.0f;
  dst[idx] = (f16)v;
}

// ---- a_msg[a][:] = sum_t msg[a2b[a][t]][:] --------------------------------
__global__ void gather_sum_kernel(const f16* __restrict__ msg,
                                  const int* __restrict__ a2b,
                                  f16* __restrict__ amsg) {
  int idx = blockIdx.x * blockDim.x + threadIdx.x;
  if (idx >= NA * (HP / 8)) return;
  int a = idx / (HP / 8);
  int c = (idx - a * (HP / 8)) * 8;
  const int* nbr = &a2b[(size_t)a * MAXNB];
  float acc[8] = {0.f, 0.f, 0.f, 0.f, 0.f, 0.f, 0.f, 0.f};
#pragma unroll
  for (int t = 0; t < MAXNB; ++t) {
    int r = nbr[t];
    f16x8 v = *(const f16x8*)&msg[(size_t)r * HP + c];
#pragma unroll
    for (int j = 0; j < 8; ++j) acc[j] += (float)v[j];
  }
  f16x8 o;
#pragma unroll
  for (int j = 0; j < 8; ++j) o[j] = (f16)acc[j];
  *(f16x8*)&amsg[(size_t)a * HP + c] = o;
}

// ---- unified GEMM: 128x320 tile, 8 waves (2x4), BK=32, 16x16x32 f16 MFMA --
// MODE 0: msg = relu(fb16 @ W_i)                                (K=160)
// MODE 1: msg' = relu([fb16[m], amsg[b2a]-msg[b2revb]] @ [W_i;W_h])  (K=480)
// MODE 2: out = relu([fa16, sum_t msg[a2b[m][t]]] @ W_o + b_o)  (K=480, fused gather)
template <int MODE>
__global__ __launch_bounds__(NTH)
void gemm_kernel(const f16* __restrict__ Afp,    // fb16 (MODE 0/1) / fa16 (MODE 2)
                 const f16* __restrict__ amsg,
                 const f16* __restrict__ msg_in,
                 const int* __restrict__ b2a,
                 const int* __restrict__ b2revb,
                 const int* __restrict__ a2b,
                 const f16* __restrict__ Wp,     // stride KP_C always
                 const float* __restrict__ b_o,
                 f16* __restrict__ out_msg,
                 float* __restrict__ out_f32) {
  constexpr int KSTEPS = (MODE == 0) ? 5 : 15;
  constexpr int M = (MODE == 2) ? NA : NB;

  __shared__ f16 As[BM][40];
  __shared__ f16 Bs[BN][40];

  const int mb = blockIdx.x;
  const int tid = threadIdx.x;
  const int lane = tid & 63, wid = tid >> 6;
  const int wr = wid >> 2, wc = wid & 3;   // 2 x 4 wave grid

  f32x4 acc[4][5] = {};

  // A staging: thread -> (row, 8-col chunk); one chunk per k-step
  const int arow = tid >> 2;
  const int ac = (tid & 3) * 8;
  const int m_g = mb * BM + arow;
  const int mrow = (m_g < M) ? m_g : 0;  // clamp: OOB rows masked in epilogue

  // B staging: 1280 chunks over 512 threads (3rd chunk partial)
  const int bidx2 = tid + 2 * NTH;
  const int br0 = tid >> 2,            bc0 = (tid & 3) * 8;
  const int br1 = (tid + NTH) >> 2,    bc1 = ((tid + NTH) & 3) * 8;
  const int br2 = bidx2 >> 2,          bc2 = (bidx2 & 3) * 8;
  const bool b2ok = bidx2 < BN * 4;

  int ra = 0, rb = 0;
  int nbr[MAXNB];
  if constexpr (MODE == 1) { ra = b2a[mrow]; rb = b2revb[mrow]; }
  if constexpr (MODE == 2) {
#pragma unroll
    for (int t = 0; t < MAXNB; ++t) nbr[t] = a2b[(size_t)mrow * MAXNB + t];
  }

  f16x8 pa, pw0, pw1, pw2;

  auto prefetch = [&](int ks) {
    const int kb = ks * BK + ac;
    if constexpr (MODE == 0) {
      pa = *(const f16x8*)&Afp[(size_t)mrow * AFP + kb];
    } else if constexpr (MODE == 1) {
      if (kb < AFP) {
        pa = *(const f16x8*)&Afp[(size_t)mrow * AFP + kb];
      } else {
        const int kk = kb - AFP;
        f16x8 x = *(const f16x8*)&amsg[(size_t)ra * HP + kk];
        f16x8 y = *(const f16x8*)&msg_in[(size_t)rb * HP + kk];
        pa = x - y;
      }
    } else {
      if (kb < AFP) {
        pa = *(const f16x8*)&Afp[(size_t)mrow * AFP + kb];
      } else {
        const int kk = kb - AFP;
        float s[8] = {0.f, 0.f, 0.f, 0.f, 0.f, 0.f, 0.f, 0.f};
#pragma unroll
        for (int t = 0; t < MAXNB; ++t) {
          f16x8 v = *(const f16x8*)&msg_in[(size_t)nbr[t] * HP + kk];
#pragma unroll
          for (int j = 0; j < 8; ++j) s[j] += (float)v[j];
        }
#pragma unroll
        for (int j = 0; j < 8; ++j) pa[j] = (f16)s[j];
      }
    }
    const int kw = ks * BK;
    pw0 = *(const f16x8*)&Wp[(size_t)br0 * KP_C + kw + bc0];
    pw1 = *(const f16x8*)&Wp[(size_t)br1 * KP_C + kw + bc1];
    if (b2ok) pw2 = *(const f16x8*)&Wp[(size_t)br2 * KP_C + kw + bc2];
  };

  prefetch(0);

  for (int ks = 0; ks < KSTEPS; ++ks) {
    __syncthreads();  // previous iteration's LDS reads done
    *(f16x8*)&As[arow][ac] = pa;
    *(f16x8*)&Bs[br0][bc0] = pw0;
    *(f16x8*)&Bs[br1][bc1] = pw1;
    if (b2ok) *(f16x8*)&Bs[br2][bc2] = pw2;
    __syncthreads();

    // issue next k-step's global loads; latency overlaps ds_read + MFMA phase
    if (ks + 1 < KSTEPS) prefetch(ks + 1);

    const int row16 = lane & 15, kh = (lane >> 4) * 8;
    f16x8 af[4], bfr[5];
#pragma unroll
    for (int m = 0; m < 4; ++m)
      af[m] = *(const f16x8*)&As[wr * 64 + m * 16 + row16][kh];
#pragma unroll
    for (int n = 0; n < 5; ++n)
      bfr[n] = *(const f16x8*)&Bs[wc * 80 + n * 16 + row16][kh];
#pragma unroll
    for (int m = 0; m < 4; ++m)
#pragma unroll
      for (int n = 0; n < 5; ++n)
        acc[m][n] = __builtin_amdgcn_mfma_f32_16x16x32_f16(af[m], bfr[n], acc[m][n], 0, 0, 0);
  }

  // epilogue: C/D layout col = lane&15, row = (lane>>4)*4 + j  [m89]
  const int row16 = lane & 15;
  const int rquad = (lane >> 4) * 4;
#pragma unroll
  for (int m = 0; m < 4; ++m) {
#pragma unroll
    for (int n = 0; n < 5; ++n) {
      const int col = wc * 80 + n * 16 + row16;   // < 320 always
#pragma unroll
      for (int j = 0; j < 4; ++j) {
        const int row = mb * BM + wr * 64 + m * 16 + rquad + j;
        float v = acc[m][n][j];
        if constexpr (MODE == 2) {
          if (row < M && col < H)
            out_f32[(size_t)row * H + col] = fmaxf(v + b_o[col], 0.0f);
        } else {
          if (row < M)
            out_msg[(size_t)row * HP + col] = (f16)fmaxf(v, 0.0f);
        }
      }
    }
  }
}

extern "C" void kernel_launch(void* const* d_in, const int* in_sizes, int n_in,
                              void* d_out, int out_size, void* d_ws, size_t ws_size,
                              hipStream_t stream) {
  const float* f_atoms = (const float*)d_in[0];
  const float* f_bonds = (const float*)d_in[1];
  const int*   a2b     = (const int*)d_in[2];
  const int*   b2a     = (const int*)d_in[3];
  const int*   b2revb  = (const int*)d_in[4];
  const float* W_i     = (const float*)d_in[5];
  const float* W_h     = (const float*)d_in[6];
  const float* W_o     = (const float*)d_in[7];
  const float* b_o     = (const float*)d_in[8];
  float* out = (float*)d_out;

  char* ws = (char*)d_ws;
  size_t off = 0;
  f16* msgA = (f16*)(ws + off); off += (size_t)NB * HP * 2;   // 128.0 MB
  f16* msgB = (f16*)(ws + off); off += (size_t)NB * HP * 2;   // 128.0 MB
  f16* amsg = (f16*)(ws + off); off += (size_t)NA * HP * 2;   //  64.0 MB
  f16* fb16 = (f16*)(ws + off); off += (size_t)NB * AFP * 2;  //  64.0 MB
  f16* fa16 = (f16*)(ws + off); off += (size_t)NA * AFP * 2;  //  32.0 MB
  f16* W1P  = (f16*)(ws + off); off += (size_t)NP * KP_C * 2;
  f16* WoP  = (f16*)(ws + off); off += (size_t)NP * KP_C * 2;
  if (off > ws_size) return;  // total ~416.6 MB

  prep_w1<<<(NP * KP_C + 255) / 256, 256, 0, stream>>>(W_i, W_h, W1P);
  prep_wo<<<(NP * KP_C + 255) / 256, 256, 0, stream>>>(W_o, WoP);
  conv_pad_f16<<<(NB * (AFP / 8) + 255) / 256, 256, 0, stream>>>(f_bonds, fb16, NB, BF);
  conv_pad_f16<<<(NA * (AFP / 8) + 255) / 256, 256, 0, stream>>>(f_atoms, fa16, NA, AF);

  const int gB = (NB + BM - 1) / BM;   // 1563
  const int gA = (NA + BM - 1) / BM;   // 782
  dim3 gS((NA * (HP / 8) + 255) / 256);

  // msgA = relu(fb16 @ W_i)
  gemm_kernel<0><<<gB, NTH, 0, stream>>>(fb16, nullptr, nullptr,
                                         nullptr, nullptr, nullptr, W1P, nullptr,
                                         msgA, nullptr);
  // iteration 1: msgB = relu(inp + (amsg[b2a]-msgA[b2revb]) @ W_h)  [fused]
  gather_sum_kernel<<<gS, 256, 0, stream>>>(msgA, a2b, amsg);
  gemm_kernel<1><<<gB, NTH, 0, stream>>>(fb16, amsg, msgA,
                                         b2a, b2revb, nullptr, W1P, nullptr,
                                         msgB, nullptr);
  // iteration 2
  gather_sum_kernel<<<gS, 256, 0, stream>>>(msgB, a2b, amsg);
  gemm_kernel<1><<<gB, NTH, 0, stream>>>(fb16, amsg, msgB,
                                         b2a, b2revb, nullptr, W1P, nullptr,
                                         msgA, nullptr);
  // readout: gather fused into the GEMM A-load
  gemm_kernel<2><<<gA, NTH, 0, stream>>>(fa16, nullptr, msgA,
                                         nullptr, nullptr, a2b, WoP, b_o,
                                         nullptr, out);
}